// Round 7
// baseline (18455.417 us; speedup 1.0000x reference)
//
#include <hip/hip_runtime.h>
#include <stdint.h>

#define TT 4096
#define INW 1024
#define HW 1024
#define OUTW 512
#define CH 2048  // HW+IN

// ws layout:
//   [0, 16KB)           : hpair[2][1024]  (uint64: epoch<<32 | float_bits)
//   [16KB, 16KB+16MB)   : h_all float[TT*HW]

__device__ __forceinline__ uint64_t pack_pair(float v, uint32_t ep) {
    return ((uint64_t)ep << 32) | (uint64_t)__float_as_uint(v);
}
__device__ __forceinline__ float sigmoid_fast(float z) {
    return 1.0f / (1.0f + __expf(-z));
}
__device__ __forceinline__ float tanh_fast(float z) {
    return 1.0f - 2.0f / (1.0f + __expf(2.0f * z));
}

// DPP wave64 sum: result lands in lane 63 (other lanes hold partials).
template <int CTRL>
__device__ __forceinline__ float dpp_add(float v) {
    int s = __builtin_amdgcn_update_dpp(0, __float_as_int(v), CTRL, 0xF, 0xF, true);
    return v + __int_as_float(s);
}
__device__ __forceinline__ float wave_sum_to_lane63(float v) {
    v = dpp_add<0x111>(v);  // row_shr:1
    v = dpp_add<0x112>(v);  // row_shr:2
    v = dpp_add<0x114>(v);  // row_shr:4
    v = dpp_add<0x118>(v);  // row_shr:8  -> lane 15/31/47/63 = row sums
    v = dpp_add<0x142>(v);  // row_bcast:15
    v = dpp_add<0x143>(v);  // row_bcast:31 -> lane 63 = total
    return v;
}

__global__ void lstm_init_kernel(uint64_t* __restrict__ hpair) {
    int j = blockIdx.x * blockDim.x + threadIdx.x;
    if (j < HW) {
        hpair[j]      = pack_pair(0.0f, 0u);          // buf0: h_0 = 0, epoch 0
        hpair[HW + j] = pack_pair(0.0f, 0x80000000u); // buf1: never-matching epoch
    }
}

#define PROBE(d0, d1, d2, d3, base)                                                   \
    do {                                                                              \
        d0 = __hip_atomic_load((base),       __ATOMIC_RELAXED, __HIP_MEMORY_SCOPE_SYSTEM); \
        d1 = __hip_atomic_load((base) + 64,  __ATOMIC_RELAXED, __HIP_MEMORY_SCOPE_SYSTEM); \
        d2 = __hip_atomic_load((base) + 128, __ATOMIC_RELAXED, __HIP_MEMORY_SCOPE_SYSTEM); \
        d3 = __hip_atomic_load((base) + 192, __ATOMIC_RELAXED, __HIP_MEMORY_SCOPE_SYSTEM); \
    } while (0)

#define EPOCH_HIT(d0, d1, d2, d3, ep)                                  \
    __all(((uint32_t)((d0) >> 32) == (ep)) & ((uint32_t)((d1) >> 32) == (ep)) & \
          ((uint32_t)((d2) >> 32) == (ep)) & ((uint32_t)((d3) >> 32) == (ep)))

// 256 blocks x 256 threads. Block b owns hidden units 4b..4b+3; wave w owns
// unit gu=4b+w (all 4 gates). Wave w polls pair-quarter [256w,256w+256) with a
// TWO-PROBE pipelined poll (detect quantum ~RTT/2); intra-block exchange via
// LDS data+flag handshake (no s_barrier => no vmcnt(0) drain of in-flight
// probes). x-matvec pipelined off the critical path (computed post-publish).
__global__ __launch_bounds__(256, 1) void lstm_seq_kernel(
    const float* __restrict__ x,
    const float* __restrict__ wf, const float* __restrict__ bf,
    const float* __restrict__ wi, const float* __restrict__ bi,
    const float* __restrict__ wc, const float* __restrict__ bc,
    const float* __restrict__ wo, const float* __restrict__ bo,
    uint64_t* __restrict__ hpair, float* __restrict__ h_all,
    float* __restrict__ out)
{
    __shared__ float hsh[2][HW];   // 8KB double-buffered h state
    __shared__ int   flg[2][4];    // flg[p][w] = t  <=>  quarter w of epoch-t state in hsh[p]

    const int tid  = threadIdx.x;
    const int lane = tid & 63;
    const int w    = tid >> 6;            // wave 0..3
    const int b    = blockIdx.x;          // 0..255
    const int gu   = b * 4 + w;           // owned hidden unit

    if (tid < 8) flg[tid >> 2][tid & 3] = -1;

    // ---- one-time: weights into registers (coalesced) ----
    float wh[64], wx[64];  // wh[g*16+k] = W_g[gu][lane+64k]; wx: +1024
    {
        const float* wptr[4] = {wf, wi, wc, wo};
#pragma unroll
        for (int g = 0; g < 4; ++g) {
            const float* base = wptr[g] + (size_t)gu * CH + lane;
#pragma unroll
            for (int k = 0; k < 16; ++k) wh[g * 16 + k] = base[(size_t)k * 64];
#pragma unroll
            for (int k = 0; k < 16; ++k) wx[g * 16 + k] = base[1024 + (size_t)k * 64];
        }
    }
#pragma unroll
    for (int i = 0; i < 64; ++i) {
        asm volatile("" : "+v"(wh[i]));
        asm volatile("" : "+v"(wx[i]));
    }

    const float bias0 = bf[gu];
    const float bias1 = bi[gu];
    const float bias2 = bc[gu];
    const float bias3 = bo[gu];

    // ---- prologue: x_0 load + its partial sums ----
    float xacc0 = 0.f, xacc1 = 0.f, xacc2 = 0.f, xacc3 = 0.f;
    {
        const float* xp = x + lane;
        float xv[16];
#pragma unroll
        for (int k = 0; k < 16; ++k) xv[k] = xp[(size_t)k * 64];
#pragma unroll
        for (int k = 0; k < 16; ++k) {
            xacc0 = fmaf(wx[0 * 16 + k], xv[k], xacc0);
            xacc1 = fmaf(wx[1 * 16 + k], xv[k], xacc1);
            xacc2 = fmaf(wx[2 * 16 + k], xv[k], xacc2);
            xacc3 = fmaf(wx[3 * 16 + k], xv[k], xacc3);
        }
    }

    __syncthreads();  // one-time: flg init visible before main loop

    float c = 0.0f, h_last = 0.0f;  // meaningful on lane 63

    // pre-issue probe set A for epoch 0 (buffer 0)
    uint64_t pa0, pa1, pa2, pa3, pb0, pb1, pb2, pb3;
    PROBE(pa0, pa1, pa2, pa3, hpair + 256 * w + lane);

    for (int t = 0; t < TT; ++t) {
        const int p = t & 1;
        const uint64_t* hp = hpair + (size_t)p * HW + 256 * w + lane;
        const uint32_t ep = (uint32_t)t;

        // ---- 1. two-probe pipelined poll: check one set while the other flies
        float hq0, hq1, hq2, hq3;
        for (;;) {
            PROBE(pb0, pb1, pb2, pb3, hp);
            __builtin_amdgcn_sched_barrier(0);  // pin: pb issued before pa's wait
            if (EPOCH_HIT(pa0, pa1, pa2, pa3, ep)) {
                hq0 = __uint_as_float((uint32_t)pa0);
                hq1 = __uint_as_float((uint32_t)pa1);
                hq2 = __uint_as_float((uint32_t)pa2);
                hq3 = __uint_as_float((uint32_t)pa3);
                break;
            }
            PROBE(pa0, pa1, pa2, pa3, hp);
            __builtin_amdgcn_sched_barrier(0);
            if (EPOCH_HIT(pb0, pb1, pb2, pb3, ep)) {
                hq0 = __uint_as_float((uint32_t)pb0);
                hq1 = __uint_as_float((uint32_t)pb1);
                hq2 = __uint_as_float((uint32_t)pb2);
                hq3 = __uint_as_float((uint32_t)pb3);
                break;
            }
        }

        // ---- 2. LDS share with flag handshake (NO s_barrier, no vmcnt drain)
        hsh[p][256 * w + lane]       = hq0;
        hsh[p][256 * w + lane + 64]  = hq1;
        hsh[p][256 * w + lane + 128] = hq2;
        hsh[p][256 * w + lane + 192] = hq3;
        asm volatile("s_waitcnt lgkmcnt(0)" ::: "memory");  // LDS-only wait
        if (lane == 0)
            __hip_atomic_store(&flg[p][w], t, __ATOMIC_RELAXED, __HIP_MEMORY_SCOPE_WORKGROUP);
        for (;;) {
            int f0 = __hip_atomic_load(&flg[p][0], __ATOMIC_RELAXED, __HIP_MEMORY_SCOPE_WORKGROUP);
            int f1 = __hip_atomic_load(&flg[p][1], __ATOMIC_RELAXED, __HIP_MEMORY_SCOPE_WORKGROUP);
            int f2 = __hip_atomic_load(&flg[p][2], __ATOMIC_RELAXED, __HIP_MEMORY_SCOPE_WORKGROUP);
            int f3 = __hip_atomic_load(&flg[p][3], __ATOMIC_RELAXED, __HIP_MEMORY_SCOPE_WORKGROUP);
            if (((f0 ^ t) | (f1 ^ t) | (f2 ^ t) | (f3 ^ t)) == 0) break;
        }
        __builtin_amdgcn_sched_barrier(0);  // data reads below stay below the spin

        // ---- 3. coalesced h_all write: hsh[p] = state entering step t -> row t-1
        if (t >= 1 && b == (t & 255)) {
            float4 hv4 = *(const float4*)&hsh[p][tid * 4];
            *(float4*)(h_all + (size_t)(t - 1) * HW + tid * 4) = hv4;
        }

        // ---- 4. h part (starts from the pipelined x partial sums) ----
        float acc0 = xacc0, acc1 = xacc1, acc2 = xacc2, acc3 = xacc3;
#pragma unroll
        for (int k = 0; k < 16; ++k) {
            float v = hsh[p][lane + 64 * k];
            acc0 = fmaf(wh[0 * 16 + k], v, acc0);
            acc1 = fmaf(wh[1 * 16 + k], v, acc1);
            acc2 = fmaf(wh[2 * 16 + k], v, acc2);
            acc3 = fmaf(wh[3 * 16 + k], v, acc3);
        }

        // ---- 5. DPP reduce to lane 63 (VALU pipe, no LDS) ----
        acc0 = wave_sum_to_lane63(acc0);
        acc1 = wave_sum_to_lane63(acc1);
        acc2 = wave_sum_to_lane63(acc2);
        acc3 = wave_sum_to_lane63(acc3);

        // ---- 6. lane 63: activations + publish epoch t+1 ----
        if (lane == 63) {
            float f  = sigmoid_fast(acc0 + bias0);
            float ii = sigmoid_fast(acc1 + bias1);
            float g  = tanh_fast(acc2 + bias2);
            float o  = sigmoid_fast(acc3 + bias3);
            c = fmaf(f, c, ii * g);
            float hn = o * tanh_fast(c);
            h_last = hn;
            __hip_atomic_store(&hpair[(size_t)((t + 1) & 1) * HW + gu],
                               pack_pair(hn, (uint32_t)(t + 1)),
                               __ATOMIC_RELAXED, __HIP_MEMORY_SCOPE_SYSTEM);
        }
        __builtin_amdgcn_sched_barrier(0);  // keep everything below the publish

        // ---- 7. pre-issue probe set A for epoch t+1 (hides first RTT) ----
        PROBE(pa0, pa1, pa2, pa3, hpair + (size_t)((t + 1) & 1) * HW + 256 * w + lane);

        // ---- 8. post-publish (slack window): x_{t+1} load + partials ----
        float xn[16];
        {
            const int tn = (t + 1 < TT) ? t + 1 : t;
            const float* xp = x + (size_t)tn * INW + lane;
#pragma unroll
            for (int k = 0; k < 16; ++k) xn[k] = xp[(size_t)k * 64];
        }
        float nx0 = 0.f, nx1 = 0.f, nx2 = 0.f, nx3 = 0.f;
#pragma unroll
        for (int k = 0; k < 16; ++k) {
            nx0 = fmaf(wx[0 * 16 + k], xn[k], nx0);
            nx1 = fmaf(wx[1 * 16 + k], xn[k], nx1);
            nx2 = fmaf(wx[2 * 16 + k], xn[k], nx2);
            nx3 = fmaf(wx[3 * 16 + k], xn[k], nx3);
        }
        xacc0 = nx0; xacc1 = nx1; xacc2 = nx2; xacc3 = nx3;
    }

    if (lane == 63) {
        // final h_all row (epoch TT is never polled by anyone)
        h_all[(size_t)(TT - 1) * HW + gu] = h_last;
        out[(size_t)TT * OUTW + gu]      = h_last;
        out[(size_t)TT * OUTW + HW + gu] = c;
    }
}

// ys[t][o] = sum_k h_all[t][k] * why[o][k] + by[o]
// grid (TT/64, OUTW/64) = (64, 8); block 256; 64x64 tile, 4x4 per thread.
__global__ __launch_bounds__(256) void lstm_ygemm_kernel(
    const float* __restrict__ hall, const float* __restrict__ why,
    const float* __restrict__ by, float* __restrict__ ys)
{
    __shared__ float hs[64][17];
    __shared__ float wsm[64][17];
    const int t0 = blockIdx.x * 64, o0 = blockIdx.y * 64;
    const int tid = threadIdx.x;
    const int tx = tid & 15, ty = tid >> 4;

    float acc[4][4] = {};
    const int r = tid >> 2;            // 0..63
    const int cc = (tid & 3) * 4;      // 0,4,8,12

    for (int kk = 0; kk < HW; kk += 16) {
        float4 hv = *(const float4*)(hall + (size_t)(t0 + r) * HW + kk + cc);
        hs[r][cc + 0] = hv.x; hs[r][cc + 1] = hv.y;
        hs[r][cc + 2] = hv.z; hs[r][cc + 3] = hv.w;
        float4 wv = *(const float4*)(why + (size_t)(o0 + r) * HW + kk + cc);
        wsm[r][cc + 0] = wv.x; wsm[r][cc + 1] = wv.y;
        wsm[r][cc + 2] = wv.z; wsm[r][cc + 3] = wv.w;
        __syncthreads();
#pragma unroll
        for (int k = 0; k < 16; ++k) {
            float ha[4], wa[4];
#pragma unroll
            for (int i = 0; i < 4; ++i) ha[i] = hs[ty * 4 + i][k];
#pragma unroll
            for (int j = 0; j < 4; ++j) wa[j] = wsm[tx * 4 + j][k];
#pragma unroll
            for (int i = 0; i < 4; ++i)
#pragma unroll
                for (int j = 0; j < 4; ++j)
                    acc[i][j] = fmaf(ha[i], wa[j], acc[i][j]);
        }
        __syncthreads();
    }
#pragma unroll
    for (int i = 0; i < 4; ++i) {
#pragma unroll
        for (int j = 0; j < 4; ++j) {
            int oo = o0 + tx * 4 + j;
            ys[(size_t)(t0 + ty * 4 + i) * OUTW + oo] = acc[i][j] + by[oo];
        }
    }
}

extern "C" void kernel_launch(void* const* d_in, const int* in_sizes, int n_in,
                              void* d_out, int out_size, void* d_ws, size_t ws_size,
                              hipStream_t stream) {
    const float* x   = (const float*)d_in[0];
    const float* wf  = (const float*)d_in[1];
    const float* bf  = (const float*)d_in[2];
    const float* wi  = (const float*)d_in[3];
    const float* bi  = (const float*)d_in[4];
    const float* wc  = (const float*)d_in[5];
    const float* bc  = (const float*)d_in[6];
    const float* wo  = (const float*)d_in[7];
    const float* bo  = (const float*)d_in[8];
    const float* why = (const float*)d_in[9];
    const float* by  = (const float*)d_in[10];
    float* out = (float*)d_out;

    uint64_t* hpair = (uint64_t*)d_ws;
    float* h_all = (float*)((char*)d_ws + (size_t)2 * HW * sizeof(uint64_t));

    lstm_init_kernel<<<dim3(4), dim3(256), 0, stream>>>(hpair);
    lstm_seq_kernel<<<dim3(256), dim3(256), 0, stream>>>(
        x, wf, bf, wi, bi, wc, bc, wo, bo, hpair, h_all, out);
    lstm_ygemm_kernel<<<dim3(64, 8), dim3(256), 0, stream>>>(h_all, why, by, out);
}

// Round 8
// 15548.538 us; speedup vs baseline: 1.1870x; 1.1870x over previous
//
#include <hip/hip_runtime.h>
#include <stdint.h>

#define TT 4096
#define INW 1024
#define HW 1024
#define OUTW 512
#define CH 2048  // HW+IN

// ws layout:
//   [0, 16KB)           : hpair[2][1024]  (uint64: epoch<<32 | float_bits)
//   [16KB, 16KB+16MB)   : h_all float[TT*HW]

typedef uint32_t u32x4 __attribute__((ext_vector_type(4)));

__device__ __forceinline__ uint64_t pack_pair(float v, uint32_t ep) {
    return ((uint64_t)ep << 32) | (uint64_t)__float_as_uint(v);
}
__device__ __forceinline__ float sigmoid_fast(float z) {
    return 1.0f / (1.0f + __expf(-z));
}
__device__ __forceinline__ float tanh_fast(float z) {
    return 1.0f - 2.0f / (1.0f + __expf(2.0f * z));
}

// DPP wave64 sum: result lands in lane 63 (other lanes hold partials).
template <int CTRL>
__device__ __forceinline__ float dpp_add(float v) {
    int s = __builtin_amdgcn_update_dpp(0, __float_as_int(v), CTRL, 0xF, 0xF, true);
    return v + __int_as_float(s);
}
__device__ __forceinline__ float wave_sum_to_lane63(float v) {
    v = dpp_add<0x111>(v);  // row_shr:1
    v = dpp_add<0x112>(v);  // row_shr:2
    v = dpp_add<0x114>(v);  // row_shr:4
    v = dpp_add<0x118>(v);  // row_shr:8  -> lane 15/31/47/63 = row sums
    v = dpp_add<0x142>(v);  // row_bcast:15
    v = dpp_add<0x143>(v);  // row_bcast:31 -> lane 63 = total
    return v;
}

__global__ void lstm_init_kernel(uint64_t* __restrict__ hpair) {
    int j = blockIdx.x * blockDim.x + threadIdx.x;
    if (j < HW) {
        hpair[j]      = pack_pair(0.0f, 0u);          // buf0: h_0 = 0, epoch 0
        hpair[HW + j] = pack_pair(0.0f, 0x80000000u); // buf1: never-matching epoch
    }
}

// Issue two 16B system-scope probes (4 pairs: j,j+1 and j+128,j+129).
// sc0 sc1 = bypass L1+L2, read the device coherence point.
#define PROBE_ISSUE(r0, r1, base)                                               \
    asm volatile("global_load_dwordx4 %0, %2, off sc0 sc1\n\t"                  \
                 "global_load_dwordx4 %1, %3, off sc0 sc1"                      \
                 : "=v"(r0), "=v"(r1)                                           \
                 : "v"((const void*)(base)), "v"((const void*)((base) + 128))   \
                 : "memory")

// Wait all VMEM, then fence the scheduler so register-only checks of r0/r1
// cannot hoist above the wait (guide rule #18).
#define PROBE_WAIT()                                             \
    do {                                                         \
        asm volatile("s_waitcnt vmcnt(0)" ::: "memory");         \
        __builtin_amdgcn_sched_barrier(0);                       \
    } while (0)

// 256 blocks x 256 threads. Block b owns hidden units 4b..4b+3; wave w owns
// unit gu=4b+w (all 4 gates). Wave w polls pair-quarter [256w,256w+256):
// lane l covers pairs {256w+2l, 256w+2l+1, 256w+128+2l, 256w+128+2l+1} via two
// dwordx4 loads (half the fabric transactions of 4x8B). Single-set wait
// discipline (R6 pacing) + post-publish pre-issue to hide the first RTT.
// Intra-block share via double-buffered LDS + one s_barrier (nothing in
// flight at the barrier => no vmcnt-drain penalty).
__global__ __launch_bounds__(256, 1) void lstm_seq_kernel(
    const float* __restrict__ x,
    const float* __restrict__ wf, const float* __restrict__ bf,
    const float* __restrict__ wi, const float* __restrict__ bi,
    const float* __restrict__ wc, const float* __restrict__ bc,
    const float* __restrict__ wo, const float* __restrict__ bo,
    uint64_t* __restrict__ hpair, float* __restrict__ h_all,
    float* __restrict__ out)
{
    __shared__ float hsh[2][HW];  // 8KB double-buffered h state

    const int tid  = threadIdx.x;
    const int lane = tid & 63;
    const int w    = tid >> 6;            // wave 0..3
    const int b    = blockIdx.x;          // 0..255
    const int gu   = b * 4 + w;           // owned hidden unit

    // ---- one-time: weights into registers (coalesced) ----
    float wh[64], wx[64];  // wh[g*16+k] = W_g[gu][lane+64k]; wx: +1024
    {
        const float* wptr[4] = {wf, wi, wc, wo};
#pragma unroll
        for (int g = 0; g < 4; ++g) {
            const float* base = wptr[g] + (size_t)gu * CH + lane;
#pragma unroll
            for (int k = 0; k < 16; ++k) wh[g * 16 + k] = base[(size_t)k * 64];
#pragma unroll
            for (int k = 0; k < 16; ++k) wx[g * 16 + k] = base[1024 + (size_t)k * 64];
        }
    }
#pragma unroll
    for (int i = 0; i < 64; ++i) {
        asm volatile("" : "+v"(wh[i]));
        asm volatile("" : "+v"(wx[i]));
    }

    const float bias0 = bf[gu];
    const float bias1 = bi[gu];
    const float bias2 = bc[gu];
    const float bias3 = bo[gu];

    // ---- prologue: x_0 load + its partial sums ----
    float xacc0 = 0.f, xacc1 = 0.f, xacc2 = 0.f, xacc3 = 0.f;
    {
        const float* xp = x + lane;
        float xv[16];
#pragma unroll
        for (int k = 0; k < 16; ++k) xv[k] = xp[(size_t)k * 64];
#pragma unroll
        for (int k = 0; k < 16; ++k) {
            xacc0 = fmaf(wx[0 * 16 + k], xv[k], xacc0);
            xacc1 = fmaf(wx[1 * 16 + k], xv[k], xacc1);
            xacc2 = fmaf(wx[2 * 16 + k], xv[k], xacc2);
            xacc3 = fmaf(wx[3 * 16 + k], xv[k], xacc3);
        }
    }

    float c = 0.0f, h_last = 0.0f;  // meaningful on lane 63

    // pre-issue probe for epoch 0 (buffer 0)
    u32x4 r0, r1;
    PROBE_ISSUE(r0, r1, hpair + 256 * w + 2 * lane);

    for (int t = 0; t < TT; ++t) {
        const int p = t & 1;
        const uint64_t* hp = hpair + (size_t)p * HW + 256 * w + 2 * lane;
        const uint32_t ep = (uint32_t)t;

        // ---- 1. poll: single-set wait discipline (R6 pacing) ----
        for (;;) {
            PROBE_WAIT();
            bool hit = __all(((r0.y == ep) & (r0.w == ep)) &
                             ((r1.y == ep) & (r1.w == ep)));
            if (hit) break;
            PROBE_ISSUE(r0, r1, hp);
        }
        const float hv0 = __uint_as_float(r0.x);  // h[256w+2l]
        const float hv1 = __uint_as_float(r0.z);  // h[256w+2l+1]
        const float hv2 = __uint_as_float(r1.x);  // h[256w+128+2l]
        const float hv3 = __uint_as_float(r1.z);  // h[256w+128+2l+1]

        // ---- 2. share quarters via LDS; single barrier per step ----
        *(float2*)&hsh[p][256 * w + 2 * lane]       = make_float2(hv0, hv1);
        *(float2*)&hsh[p][256 * w + 128 + 2 * lane] = make_float2(hv2, hv3);
        __syncthreads();
        // (no 2nd barrier: hsh[p] is next written at t+2; passing the poll for
        //  epoch t+2 implies every block passed step t+1, which is after all
        //  step-t reads of hsh[p]. Double-buffer + induction.)

        // ---- 3. coalesced h_all write: hsh[p] = state entering step t -> row t-1
        if (t >= 1 && b == (t & 255)) {
            float4 hv4 = *(const float4*)&hsh[p][tid * 4];
            *(float4*)(h_all + (size_t)(t - 1) * HW + tid * 4) = hv4;
        }

        // ---- 4. h part (starts from the pipelined x partial sums) ----
        float acc0 = xacc0, acc1 = xacc1, acc2 = xacc2, acc3 = xacc3;
#pragma unroll
        for (int k = 0; k < 16; ++k) {
            float v = hsh[p][lane + 64 * k];
            acc0 = fmaf(wh[0 * 16 + k], v, acc0);
            acc1 = fmaf(wh[1 * 16 + k], v, acc1);
            acc2 = fmaf(wh[2 * 16 + k], v, acc2);
            acc3 = fmaf(wh[3 * 16 + k], v, acc3);
        }

        // ---- 5. DPP reduce to lane 63 (VALU pipe, no LDS) ----
        acc0 = wave_sum_to_lane63(acc0);
        acc1 = wave_sum_to_lane63(acc1);
        acc2 = wave_sum_to_lane63(acc2);
        acc3 = wave_sum_to_lane63(acc3);

        // ---- 6. lane 63: activations + publish epoch t+1 ----
        if (lane == 63) {
            float f  = sigmoid_fast(acc0 + bias0);
            float ii = sigmoid_fast(acc1 + bias1);
            float g  = tanh_fast(acc2 + bias2);
            float o  = sigmoid_fast(acc3 + bias3);
            c = fmaf(f, c, ii * g);
            float hn = o * tanh_fast(c);
            h_last = hn;
            __hip_atomic_store(&hpair[(size_t)((t + 1) & 1) * HW + gu],
                               pack_pair(hn, (uint32_t)(t + 1)),
                               __ATOMIC_RELAXED, __HIP_MEMORY_SCOPE_SYSTEM);
        }
        __builtin_amdgcn_sched_barrier(0);  // keep everything below the publish

        // ---- 7. pre-issue the epoch-t+1 probe: flies during the slack window;
        //         in-order vmcnt means it is complete by the next loop-top wait.
        PROBE_ISSUE(r0, r1, hpair + (size_t)((t + 1) & 1) * HW + 256 * w + 2 * lane);

        // ---- 8. post-publish (slack window): x_{t+1} load + partials ----
        float xn[16];
        {
            const int tn = (t + 1 < TT) ? t + 1 : t;
            const float* xp = x + (size_t)tn * INW + lane;
#pragma unroll
            for (int k = 0; k < 16; ++k) xn[k] = xp[(size_t)k * 64];
        }
        float nx0 = 0.f, nx1 = 0.f, nx2 = 0.f, nx3 = 0.f;
#pragma unroll
        for (int k = 0; k < 16; ++k) {
            nx0 = fmaf(wx[0 * 16 + k], xn[k], nx0);
            nx1 = fmaf(wx[1 * 16 + k], xn[k], nx1);
            nx2 = fmaf(wx[2 * 16 + k], xn[k], nx2);
            nx3 = fmaf(wx[3 * 16 + k], xn[k], nx3);
        }
        xacc0 = nx0; xacc1 = nx1; xacc2 = nx2; xacc3 = nx3;
    }

    if (lane == 63) {
        // final h_all row (epoch TT is never polled by anyone)
        h_all[(size_t)(TT - 1) * HW + gu] = h_last;
        out[(size_t)TT * OUTW + gu]      = h_last;
        out[(size_t)TT * OUTW + HW + gu] = c;
    }
}

// ys[t][o] = sum_k h_all[t][k] * why[o][k] + by[o]
// grid (TT/64, OUTW/64) = (64, 8); block 256; 64x64 tile, 4x4 per thread.
__global__ __launch_bounds__(256) void lstm_ygemm_kernel(
    const float* __restrict__ hall, const float* __restrict__ why,
    const float* __restrict__ by, float* __restrict__ ys)
{
    __shared__ float hs[64][17];
    __shared__ float wsm[64][17];
    const int t0 = blockIdx.x * 64, o0 = blockIdx.y * 64;
    const int tid = threadIdx.x;
    const int tx = tid & 15, ty = tid >> 4;

    float acc[4][4] = {};
    const int r = tid >> 2;            // 0..63
    const int cc = (tid & 3) * 4;      // 0,4,8,12

    for (int kk = 0; kk < HW; kk += 16) {
        float4 hv = *(const float4*)(hall + (size_t)(t0 + r) * HW + kk + cc);
        hs[r][cc + 0] = hv.x; hs[r][cc + 1] = hv.y;
        hs[r][cc + 2] = hv.z; hs[r][cc + 3] = hv.w;
        float4 wv = *(const float4*)(why + (size_t)(o0 + r) * HW + kk + cc);
        wsm[r][cc + 0] = wv.x; wsm[r][cc + 1] = wv.y;
        wsm[r][cc + 2] = wv.z; wsm[r][cc + 3] = wv.w;
        __syncthreads();
#pragma unroll
        for (int k = 0; k < 16; ++k) {
            float ha[4], wa[4];
#pragma unroll
            for (int i = 0; i < 4; ++i) ha[i] = hs[ty * 4 + i][k];
#pragma unroll
            for (int j = 0; j < 4; ++j) wa[j] = wsm[tx * 4 + j][k];
#pragma unroll
            for (int i = 0; i < 4; ++i)
#pragma unroll
                for (int j = 0; j < 4; ++j)
                    acc[i][j] = fmaf(ha[i], wa[j], acc[i][j]);
        }
        __syncthreads();
    }
#pragma unroll
    for (int i = 0; i < 4; ++i) {
#pragma unroll
        for (int j = 0; j < 4; ++j) {
            int oo = o0 + tx * 4 + j;
            ys[(size_t)(t0 + ty * 4 + i) * OUTW + oo] = acc[i][j] + by[oo];
        }
    }
}

extern "C" void kernel_launch(void* const* d_in, const int* in_sizes, int n_in,
                              void* d_out, int out_size, void* d_ws, size_t ws_size,
                              hipStream_t stream) {
    const float* x   = (const float*)d_in[0];
    const float* wf  = (const float*)d_in[1];
    const float* bf  = (const float*)d_in[2];
    const float* wi  = (const float*)d_in[3];
    const float* bi  = (const float*)d_in[4];
    const float* wc  = (const float*)d_in[5];
    const float* bc  = (const float*)d_in[6];
    const float* wo  = (const float*)d_in[7];
    const float* bo  = (const float*)d_in[8];
    const float* why = (const float*)d_in[9];
    const float* by  = (const float*)d_in[10];
    float* out = (float*)d_out;

    uint64_t* hpair = (uint64_t*)d_ws;
    float* h_all = (float*)((char*)d_ws + (size_t)2 * HW * sizeof(uint64_t));

    lstm_init_kernel<<<dim3(4), dim3(256), 0, stream>>>(hpair);
    lstm_seq_kernel<<<dim3(256), dim3(256), 0, stream>>>(
        x, wf, bf, wi, bi, wc, bc, wo, bo, hpair, h_all, out);
    lstm_ygemm_kernel<<<dim3(64, 8), dim3(256), 0, stream>>>(h_all, why, by, out);
}

// Round 9
// 10735.722 us; speedup vs baseline: 1.7191x; 1.4483x over previous
//
#include <hip/hip_runtime.h>
#include <stdint.h>

#define TT 4096
#define INW 1024
#define HW 1024
#define OUTW 512
#define CH 2048  // HW+IN

// ws layout:
//   [0, 16KB)           : hpair[2][1024]  (uint64: epoch<<32 | float_bits)
//   [16KB, 16KB+16MB)   : h_all float[TT*HW]

typedef uint32_t u32x4 __attribute__((ext_vector_type(4)));

__device__ __forceinline__ uint64_t pack_pair(float v, uint32_t ep) {
    return ((uint64_t)ep << 32) | (uint64_t)__float_as_uint(v);
}
__device__ __forceinline__ float sigmoid_fast(float z) {
    return 1.0f / (1.0f + __expf(-z));
}
__device__ __forceinline__ float tanh_fast(float z) {
    return 1.0f - 2.0f / (1.0f + __expf(2.0f * z));
}

// DPP wave64 sum: result lands in lane 63 (other lanes hold partials).
template <int CTRL>
__device__ __forceinline__ float dpp_add(float v) {
    int s = __builtin_amdgcn_update_dpp(0, __float_as_int(v), CTRL, 0xF, 0xF, true);
    return v + __int_as_float(s);
}
__device__ __forceinline__ float wave_sum_to_lane63(float v) {
    v = dpp_add<0x111>(v);  // row_shr:1
    v = dpp_add<0x112>(v);  // row_shr:2
    v = dpp_add<0x114>(v);  // row_shr:4
    v = dpp_add<0x118>(v);  // row_shr:8  -> lane 15/31/47/63 = row sums
    v = dpp_add<0x142>(v);  // row_bcast:15
    v = dpp_add<0x143>(v);  // row_bcast:31 -> lane 63 = total
    return v;
}

__global__ void lstm_init_kernel(uint64_t* __restrict__ hpair) {
    int j = blockIdx.x * blockDim.x + threadIdx.x;
    if (j < HW) {
        hpair[j]      = pack_pair(0.0f, 0u);          // buf0: h_0 = 0, epoch 0
        hpair[HW + j] = pack_pair(0.0f, 0x80000000u); // buf1: never-matching epoch
    }
}

// 128 blocks x 256 threads. Block b owns hidden units 8b..8b+7; wave w owns
// the ADJACENT pair gu0=8b+2w, gu1=gu0+1 (all 4 gates each).
// Wave w polls pair-quarter [256w,256w+256) exactly as R6 (4x8B system-scope
// atomic loads per lane, single-round-in-flight pacing), shares via
// double-buffered LDS + one barrier. Publish: ONE dwordx4 sc0 sc1 store
// carrying both (value,epoch) pairs. Halves fabric transactions and the
// straggler population vs R6 at +~0.12us/step of extra per-wave compute.
__global__ __launch_bounds__(256, 1) void lstm_seq_kernel(
    const float* __restrict__ x,
    const float* __restrict__ wf, const float* __restrict__ bf,
    const float* __restrict__ wi, const float* __restrict__ bi,
    const float* __restrict__ wc, const float* __restrict__ bc,
    const float* __restrict__ wo, const float* __restrict__ bo,
    uint64_t* __restrict__ hpair, float* __restrict__ h_all,
    float* __restrict__ out)
{
    __shared__ float hsh[2][HW];  // 8KB double-buffered h state

    const int tid  = threadIdx.x;
    const int lane = tid & 63;
    const int w    = tid >> 6;            // wave 0..3
    const int b    = blockIdx.x;          // 0..127
    const int gu0  = b * 8 + 2 * w;       // first owned unit (even)
    // units gu0, gu0+1 are adjacent -> one 16B publish store

    // ---- one-time: weights into registers (coalesced) ----
    // wh[u*64 + g*16 + k] = W_g[gu0+u][lane + 64k]; wx same at col+1024
    float wh[128], wx[128];
    {
        const float* wptr[4] = {wf, wi, wc, wo};
#pragma unroll
        for (int u = 0; u < 2; ++u) {
#pragma unroll
            for (int g = 0; g < 4; ++g) {
                const float* base = wptr[g] + (size_t)(gu0 + u) * CH + lane;
#pragma unroll
                for (int k = 0; k < 16; ++k) wh[u * 64 + g * 16 + k] = base[(size_t)k * 64];
#pragma unroll
                for (int k = 0; k < 16; ++k) wx[u * 64 + g * 16 + k] = base[1024 + (size_t)k * 64];
            }
        }
    }
#pragma unroll
    for (int i = 0; i < 128; ++i) {
        asm volatile("" : "+v"(wh[i]));
        asm volatile("" : "+v"(wx[i]));
    }

    float bias[8];
#pragma unroll
    for (int u = 0; u < 2; ++u) {
        bias[u * 4 + 0] = bf[gu0 + u];
        bias[u * 4 + 1] = bi[gu0 + u];
        bias[u * 4 + 2] = bc[gu0 + u];
        bias[u * 4 + 3] = bo[gu0 + u];
    }

    // ---- prologue: x_0 load + its partial sums ----
    float xacc[8] = {0.f, 0.f, 0.f, 0.f, 0.f, 0.f, 0.f, 0.f};
    {
        const float* xp = x + lane;
        float xv[16];
#pragma unroll
        for (int k = 0; k < 16; ++k) xv[k] = xp[(size_t)k * 64];
#pragma unroll
        for (int k = 0; k < 16; ++k) {
#pragma unroll
            for (int j = 0; j < 8; ++j)
                xacc[j] = fmaf(wx[(j >> 2) * 64 + (j & 3) * 16 + k], xv[k], xacc[j]);
        }
    }

    float c0 = 0.f, c1 = 0.f, h0_last = 0.f, h1_last = 0.f;  // lane 63

    for (int t = 0; t < TT; ++t) {
        const int p = t & 1;

        // ---- 1. poll my quarter (R6-proven pacing: single round in flight) --
        const uint64_t* hp = hpair + (size_t)p * HW + 256 * w + lane;
        float hq[4];
        {
            bool ok;
            do {
                uint64_t pv[4];
#pragma unroll
                for (int k = 0; k < 4; ++k)
                    pv[k] = __hip_atomic_load(&hp[64 * k],
                                              __ATOMIC_RELAXED, __HIP_MEMORY_SCOPE_SYSTEM);
                ok = true;
#pragma unroll
                for (int k = 0; k < 4; ++k)
                    ok &= ((uint32_t)(pv[k] >> 32) == (uint32_t)t);
#pragma unroll
                for (int k = 0; k < 4; ++k)
                    hq[k] = __uint_as_float((uint32_t)pv[k]);
            } while (!__all(ok));
        }

        // ---- 2. share quarters via LDS; single barrier per step ----
#pragma unroll
        for (int k = 0; k < 4; ++k)
            hsh[p][256 * w + lane + 64 * k] = hq[k];
        __syncthreads();
        // (Buffer-reuse safety: passing this barrier requires all 4 quarters
        //  at epoch t => ALL blocks published t => all completed step t-1.
        //  hpair[p] / hsh[p] are only rewritten 2 epochs later. Induction.)

        // ---- 3. prefetch x_{t+1} AFTER the barrier ----
        float xn[16];
        {
            const int tn = (t + 1 < TT) ? t + 1 : t;
            const float* xp = x + (size_t)tn * INW + lane;
#pragma unroll
            for (int k = 0; k < 16; ++k) xn[k] = xp[(size_t)k * 64];
        }

        // ---- 4. coalesced h_all write: hsh[p] = state entering t -> row t-1
        if (t >= 1 && b == (t & 127)) {
            float4 hv4 = *(const float4*)&hsh[p][tid * 4];
            *(float4*)(h_all + (size_t)(t - 1) * HW + tid * 4) = hv4;
        }

        // ---- 5. h part (starts from the pipelined x partial sums) ----
        float acc[8];
#pragma unroll
        for (int j = 0; j < 8; ++j) acc[j] = xacc[j];
#pragma unroll
        for (int k = 0; k < 16; ++k) {
            float v = hsh[p][lane + 64 * k];
#pragma unroll
            for (int j = 0; j < 8; ++j)
                acc[j] = fmaf(wh[(j >> 2) * 64 + (j & 3) * 16 + k], v, acc[j]);
        }

        // ---- 6. DPP reduce all 8 sums to lane 63 ----
#pragma unroll
        for (int j = 0; j < 8; ++j) acc[j] = wave_sum_to_lane63(acc[j]);

        // ---- 7. lane 63: activations + ONE dwordx4 publish (2 pairs) ----
        if (lane == 63) {
            float f0  = sigmoid_fast(acc[0] + bias[0]);
            float i0  = sigmoid_fast(acc[1] + bias[1]);
            float g0  = tanh_fast(acc[2] + bias[2]);
            float o0  = sigmoid_fast(acc[3] + bias[3]);
            c0 = fmaf(f0, c0, i0 * g0);
            float hn0 = o0 * tanh_fast(c0);
            float f1  = sigmoid_fast(acc[4] + bias[4]);
            float i1  = sigmoid_fast(acc[5] + bias[5]);
            float g1  = tanh_fast(acc[6] + bias[6]);
            float o1  = sigmoid_fast(acc[7] + bias[7]);
            c1 = fmaf(f1, c1, i1 * g1);
            float hn1 = o1 * tanh_fast(c1);
            h0_last = hn0; h1_last = hn1;
            const uint32_t ep1 = (uint32_t)(t + 1);
            u32x4 st;
            st.x = __float_as_uint(hn0); st.y = ep1;
            st.z = __float_as_uint(hn1); st.w = ep1;
            uint64_t* dst = hpair + (size_t)((t + 1) & 1) * HW + gu0;  // 16B aligned (gu0 even)
            asm volatile("global_store_dwordx4 %0, %1, off sc0 sc1"
                         :: "v"((void*)dst), "v"(st) : "memory");
        }
        __builtin_amdgcn_sched_barrier(0);  // keep xacc recompute below publish

        // ---- 8. post-publish (slack window): x partials for t+1 ----
        float nx[8] = {0.f, 0.f, 0.f, 0.f, 0.f, 0.f, 0.f, 0.f};
#pragma unroll
        for (int k = 0; k < 16; ++k) {
#pragma unroll
            for (int j = 0; j < 8; ++j)
                nx[j] = fmaf(wx[(j >> 2) * 64 + (j & 3) * 16 + k], xn[k], nx[j]);
        }
#pragma unroll
        for (int j = 0; j < 8; ++j) xacc[j] = nx[j];
    }

    if (lane == 63) {
        // final h_all row (epoch TT is never polled by anyone)
        h_all[(size_t)(TT - 1) * HW + gu0]     = h0_last;
        h_all[(size_t)(TT - 1) * HW + gu0 + 1] = h1_last;
        out[(size_t)TT * OUTW + gu0]           = h0_last;
        out[(size_t)TT * OUTW + gu0 + 1]       = h1_last;
        out[(size_t)TT * OUTW + HW + gu0]      = c0;
        out[(size_t)TT * OUTW + HW + gu0 + 1]  = c1;
    }
}

// ys[t][o] = sum_k h_all[t][k] * why[o][k] + by[o]
// grid (TT/64, OUTW/64) = (64, 8); block 256; 64x64 tile, 4x4 per thread.
__global__ __launch_bounds__(256) void lstm_ygemm_kernel(
    const float* __restrict__ hall, const float* __restrict__ why,
    const float* __restrict__ by, float* __restrict__ ys)
{
    __shared__ float hs[64][17];
    __shared__ float wsm[64][17];
    const int t0 = blockIdx.x * 64, o0 = blockIdx.y * 64;
    const int tid = threadIdx.x;
    const int tx = tid & 15, ty = tid >> 4;

    float acc[4][4] = {};
    const int r = tid >> 2;            // 0..63
    const int cc = (tid & 3) * 4;      // 0,4,8,12

    for (int kk = 0; kk < HW; kk += 16) {
        float4 hv = *(const float4*)(hall + (size_t)(t0 + r) * HW + kk + cc);
        hs[r][cc + 0] = hv.x; hs[r][cc + 1] = hv.y;
        hs[r][cc + 2] = hv.z; hs[r][cc + 3] = hv.w;
        float4 wv = *(const float4*)(why + (size_t)(o0 + r) * HW + kk + cc);
        wsm[r][cc + 0] = wv.x; wsm[r][cc + 1] = wv.y;
        wsm[r][cc + 2] = wv.z; wsm[r][cc + 3] = wv.w;
        __syncthreads();
#pragma unroll
        for (int k = 0; k < 16; ++k) {
            float ha[4], wa[4];
#pragma unroll
            for (int i = 0; i < 4; ++i) ha[i] = hs[ty * 4 + i][k];
#pragma unroll
            for (int j = 0; j < 4; ++j) wa[j] = wsm[tx * 4 + j][k];
#pragma unroll
            for (int i = 0; i < 4; ++i)
#pragma unroll
                for (int j = 0; j < 4; ++j)
                    acc[i][j] = fmaf(ha[i], wa[j], acc[i][j]);
        }
        __syncthreads();
    }
#pragma unroll
    for (int i = 0; i < 4; ++i) {
#pragma unroll
        for (int j = 0; j < 4; ++j) {
            int oo = o0 + tx * 4 + j;
            ys[(size_t)(t0 + ty * 4 + i) * OUTW + oo] = acc[i][j] + by[oo];
        }
    }
}

extern "C" void kernel_launch(void* const* d_in, const int* in_sizes, int n_in,
                              void* d_out, int out_size, void* d_ws, size_t ws_size,
                              hipStream_t stream) {
    const float* x   = (const float*)d_in[0];
    const float* wf  = (const float*)d_in[1];
    const float* bf  = (const float*)d_in[2];
    const float* wi  = (const float*)d_in[3];
    const float* bi  = (const float*)d_in[4];
    const float* wc  = (const float*)d_in[5];
    const float* bc  = (const float*)d_in[6];
    const float* wo  = (const float*)d_in[7];
    const float* bo  = (const float*)d_in[8];
    const float* why = (const float*)d_in[9];
    const float* by  = (const float*)d_in[10];
    float* out = (float*)d_out;

    uint64_t* hpair = (uint64_t*)d_ws;
    float* h_all = (float*)((char*)d_ws + (size_t)2 * HW * sizeof(uint64_t));

    lstm_init_kernel<<<dim3(4), dim3(256), 0, stream>>>(hpair);
    lstm_seq_kernel<<<dim3(128), dim3(256), 0, stream>>>(
        x, wf, bf, wi, bi, wc, bc, wo, bo, hpair, h_all, out);
    lstm_ygemm_kernel<<<dim3(64, 8), dim3(256), 0, stream>>>(h_all, why, by, out);
}

// Round 10
// 6773.159 us; speedup vs baseline: 2.7248x; 1.5850x over previous
//
#include <hip/hip_runtime.h>
#include <stdint.h>

#define TT 4096
#define INW 1024
#define HW 1024
#define OUTW 512
#define CH 2048  // HW+IN

// ws layout:
//   [0, 16KB)           : hpair[2][1024]  (uint64: epoch<<32 | float_bits)
//   [16KB, 16KB+16MB)   : h_all float[TT*HW]

__device__ __forceinline__ uint64_t pack_pair(float v, uint32_t ep) {
    return ((uint64_t)ep << 32) | (uint64_t)__float_as_uint(v);
}
__device__ __forceinline__ float sigmoid_fast(float z) {
    return 1.0f / (1.0f + __expf(-z));
}
__device__ __forceinline__ float tanh_fast(float z) {
    return 1.0f - 2.0f / (1.0f + __expf(2.0f * z));
}

// DPP wave64 sum: result lands in lane 63 (other lanes hold partials).
template <int CTRL>
__device__ __forceinline__ float dpp_add(float v) {
    int s = __builtin_amdgcn_update_dpp(0, __float_as_int(v), CTRL, 0xF, 0xF, true);
    return v + __int_as_float(s);
}
__device__ __forceinline__ float wave_sum_to_lane63(float v) {
    v = dpp_add<0x111>(v);  // row_shr:1
    v = dpp_add<0x112>(v);  // row_shr:2
    v = dpp_add<0x114>(v);  // row_shr:4
    v = dpp_add<0x118>(v);  // row_shr:8  -> lane 15/31/47/63 = row sums
    v = dpp_add<0x142>(v);  // row_bcast:15
    v = dpp_add<0x143>(v);  // row_bcast:31 -> lane 63 = total
    return v;
}

__global__ void lstm_init_kernel(uint64_t* __restrict__ hpair) {
    int j = blockIdx.x * blockDim.x + threadIdx.x;
    if (j < HW) {
        hpair[j]      = pack_pair(0.0f, 0u);          // buf0: h_0 = 0, epoch 0
        hpair[HW + j] = pack_pair(0.0f, 0x80000000u); // buf1: never-matching epoch
    }
}

// 256 blocks x 256 threads (R6-proven topology). Block b owns hidden units
// 4b..4b+3; wave w owns unit gu=4b+w (all 4 gates). Wave w polls pair-quarter
// [256w,256w+256) with R6's issue-at-need single-round pacing.
// Ring-shorteners vs R6: (1) bias folded into xacc (slack), (2) own-quarter
// FMA runs PRE-barrier (wh register layout permuted own-quarter-first so all
// register indices stay static -> no scratch).
__global__ __launch_bounds__(256, 1) void lstm_seq_kernel(
    const float* __restrict__ x,
    const float* __restrict__ wf, const float* __restrict__ bf,
    const float* __restrict__ wi, const float* __restrict__ bi,
    const float* __restrict__ wc, const float* __restrict__ bc,
    const float* __restrict__ wo, const float* __restrict__ bo,
    uint64_t* __restrict__ hpair, float* __restrict__ h_all,
    float* __restrict__ out)
{
    __shared__ float hsh[2][HW];  // 8KB double-buffered h state

    const int tid  = threadIdx.x;
    const int lane = tid & 63;
    const int w    = tid >> 6;            // wave 0..3
    const int b    = blockIdx.x;          // 0..255
    const int gu   = b * 4 + w;           // owned hidden unit

    // ---- own-quarter-first column permutation: slot s -> column k ----
    // s in [0,4):  k = 4w+s              (wave's own polled quarter)
    // s in [4,16): k = 4*((w+1+((s-4)>>2))&3) + (s&3)   (quarters w+1,w+2,w+3)
    int kmap[16];
#pragma unroll
    for (int s = 0; s < 4; ++s) kmap[s] = 4 * w + s;
#pragma unroll
    for (int s = 4; s < 16; ++s) kmap[s] = 4 * ((w + 1 + ((s - 4) >> 2)) & 3) + (s & 3);

    // ---- one-time: weights into registers (coalesced within each k-column) --
    float wh[64], wx[64];  // wh[g*16+s] = W_g[gu][lane + 64*kmap[s]]; wx natural order
    {
        const float* wptr[4] = {wf, wi, wc, wo};
#pragma unroll
        for (int g = 0; g < 4; ++g) {
            const float* base = wptr[g] + (size_t)gu * CH + lane;
#pragma unroll
            for (int s = 0; s < 16; ++s) wh[g * 16 + s] = base[(size_t)kmap[s] * 64];
#pragma unroll
            for (int k = 0; k < 16; ++k) wx[g * 16 + k] = base[1024 + (size_t)k * 64];
        }
    }
#pragma unroll
    for (int i = 0; i < 64; ++i) {
        asm volatile("" : "+v"(wh[i]));
        asm volatile("" : "+v"(wx[i]));
    }

    const float bias0 = bf[gu];
    const float bias1 = bi[gu];
    const float bias2 = bc[gu];
    const float bias3 = bo[gu];

    // ---- prologue: x_0 load + its partial sums (bias seeded on lane 63) ----
    float xacc0 = (lane == 63) ? bias0 : 0.f;
    float xacc1 = (lane == 63) ? bias1 : 0.f;
    float xacc2 = (lane == 63) ? bias2 : 0.f;
    float xacc3 = (lane == 63) ? bias3 : 0.f;
    {
        const float* xp = x + lane;
        float xv[16];
#pragma unroll
        for (int k = 0; k < 16; ++k) xv[k] = xp[(size_t)k * 64];
#pragma unroll
        for (int k = 0; k < 16; ++k) {
            xacc0 = fmaf(wx[0 * 16 + k], xv[k], xacc0);
            xacc1 = fmaf(wx[1 * 16 + k], xv[k], xacc1);
            xacc2 = fmaf(wx[2 * 16 + k], xv[k], xacc2);
            xacc3 = fmaf(wx[3 * 16 + k], xv[k], xacc3);
        }
    }

    float c = 0.0f, h_last = 0.0f;  // meaningful on lane 63

    for (int t = 0; t < TT; ++t) {
        const int p = t & 1;

        // ---- 1. poll my quarter (R6 pacing: single round in flight) ----
        const uint64_t* hp = hpair + (size_t)p * HW + 256 * w + lane;
        float hq[4];
        {
            bool ok;
            do {
                uint64_t pv[4];
#pragma unroll
                for (int k = 0; k < 4; ++k)
                    pv[k] = __hip_atomic_load(&hp[64 * k],
                                              __ATOMIC_RELAXED, __HIP_MEMORY_SCOPE_SYSTEM);
                ok = true;
#pragma unroll
                for (int k = 0; k < 4; ++k)
                    ok &= ((uint32_t)(pv[k] >> 32) == (uint32_t)t);
#pragma unroll
                for (int k = 0; k < 4; ++k)
                    hq[k] = __uint_as_float((uint32_t)pv[k]);
            } while (!__all(ok));
        }

        // ---- 2. LDS share + PRE-BARRIER own-quarter FMA (overlaps sibling
        //         stragglers; hq[j] = h[256w+lane+64j] pairs with wh slot j) --
#pragma unroll
        for (int k = 0; k < 4; ++k)
            hsh[p][256 * w + lane + 64 * k] = hq[k];

        float acc0 = xacc0, acc1 = xacc1, acc2 = xacc2, acc3 = xacc3;
#pragma unroll
        for (int j = 0; j < 4; ++j) {
            acc0 = fmaf(wh[0 * 16 + j], hq[j], acc0);
            acc1 = fmaf(wh[1 * 16 + j], hq[j], acc1);
            acc2 = fmaf(wh[2 * 16 + j], hq[j], acc2);
            acc3 = fmaf(wh[3 * 16 + j], hq[j], acc3);
        }
        __syncthreads();
        // (no 2nd barrier: hsh[p] is next written at t+2; passing the poll for
        //  epoch t+2 implies every block passed step t+1, which is after all
        //  step-t reads of hsh[p]. Double-buffer + induction.)

        // ---- 3. prefetch x_{t+1} AFTER the barrier (not drained by it) ----
        float xn[16];
        {
            const int tn = (t + 1 < TT) ? t + 1 : t;
            const float* xp = x + (size_t)tn * INW + lane;
#pragma unroll
            for (int k = 0; k < 16; ++k) xn[k] = xp[(size_t)k * 64];
        }

        // ---- 4. coalesced h_all write: hsh[p] = state entering t -> row t-1
        if (t >= 1 && b == (t & 255)) {
            float4 hv4 = *(const float4*)&hsh[p][tid * 4];
            *(float4*)(h_all + (size_t)(t - 1) * HW + tid * 4) = hv4;
        }

        // ---- 5. h part: remaining 3 quarters (static wh slots 4..15) ----
#pragma unroll
        for (int i = 0; i < 3; ++i) {
            const int q = (w + 1 + i) & 3;                 // wave-uniform
            const float* hrow = &hsh[p][256 * q + lane];
#pragma unroll
            for (int j = 0; j < 4; ++j) {
                const float v = hrow[64 * j];
                const int s = 4 + i * 4 + j;               // static index
                acc0 = fmaf(wh[0 * 16 + s], v, acc0);
                acc1 = fmaf(wh[1 * 16 + s], v, acc1);
                acc2 = fmaf(wh[2 * 16 + s], v, acc2);
                acc3 = fmaf(wh[3 * 16 + s], v, acc3);
            }
        }

        // ---- 6. DPP reduce to lane 63 (VALU pipe, no LDS) ----
        acc0 = wave_sum_to_lane63(acc0);
        acc1 = wave_sum_to_lane63(acc1);
        acc2 = wave_sum_to_lane63(acc2);
        acc3 = wave_sum_to_lane63(acc3);

        // ---- 7. lane 63: activations (bias already in acc) + publish t+1 ----
        if (lane == 63) {
            float f  = sigmoid_fast(acc0);
            float ii = sigmoid_fast(acc1);
            float g  = tanh_fast(acc2);
            float o  = sigmoid_fast(acc3);
            c = fmaf(f, c, ii * g);
            float hn = o * tanh_fast(c);
            h_last = hn;
            __hip_atomic_store(&hpair[(size_t)((t + 1) & 1) * HW + gu],
                               pack_pair(hn, (uint32_t)(t + 1)),
                               __ATOMIC_RELAXED, __HIP_MEMORY_SCOPE_SYSTEM);
        }
        __builtin_amdgcn_sched_barrier(0);  // keep xacc recompute below publish

        // ---- 8. post-publish (slack window): x partials for t+1 + bias seed --
        float nx0 = (lane == 63) ? bias0 : 0.f;
        float nx1 = (lane == 63) ? bias1 : 0.f;
        float nx2 = (lane == 63) ? bias2 : 0.f;
        float nx3 = (lane == 63) ? bias3 : 0.f;
#pragma unroll
        for (int k = 0; k < 16; ++k) {
            nx0 = fmaf(wx[0 * 16 + k], xn[k], nx0);
            nx1 = fmaf(wx[1 * 16 + k], xn[k], nx1);
            nx2 = fmaf(wx[2 * 16 + k], xn[k], nx2);
            nx3 = fmaf(wx[3 * 16 + k], xn[k], nx3);
        }
        xacc0 = nx0; xacc1 = nx1; xacc2 = nx2; xacc3 = nx3;
    }

    if (lane == 63) {
        // final h_all row (epoch TT is never polled by anyone)
        h_all[(size_t)(TT - 1) * HW + gu] = h_last;
        out[(size_t)TT * OUTW + gu]      = h_last;
        out[(size_t)TT * OUTW + HW + gu] = c;
    }
}

// ys[t][o] = sum_k h_all[t][k] * why[o][k] + by[o]
// grid (TT/64, OUTW/64) = (64, 8); block 256; 64x64 tile, 4x4 per thread.
__global__ __launch_bounds__(256) void lstm_ygemm_kernel(
    const float* __restrict__ hall, const float* __restrict__ why,
    const float* __restrict__ by, float* __restrict__ ys)
{
    __shared__ float hs[64][17];
    __shared__ float wsm[64][17];
    const int t0 = blockIdx.x * 64, o0 = blockIdx.y * 64;
    const int tid = threadIdx.x;
    const int tx = tid & 15, ty = tid >> 4;

    float acc[4][4] = {};
    const int r = tid >> 2;            // 0..63
    const int cc = (tid & 3) * 4;      // 0,4,8,12

    for (int kk = 0; kk < HW; kk += 16) {
        float4 hv = *(const float4*)(hall + (size_t)(t0 + r) * HW + kk + cc);
        hs[r][cc + 0] = hv.x; hs[r][cc + 1] = hv.y;
        hs[r][cc + 2] = hv.z; hs[r][cc + 3] = hv.w;
        float4 wv = *(const float4*)(why + (size_t)(o0 + r) * HW + kk + cc);
        wsm[r][cc + 0] = wv.x; wsm[r][cc + 1] = wv.y;
        wsm[r][cc + 2] = wv.z; wsm[r][cc + 3] = wv.w;
        __syncthreads();
#pragma unroll
        for (int k = 0; k < 16; ++k) {
            float ha[4], wa[4];
#pragma unroll
            for (int i = 0; i < 4; ++i) ha[i] = hs[ty * 4 + i][k];
#pragma unroll
            for (int j = 0; j < 4; ++j) wa[j] = wsm[tx * 4 + j][k];
#pragma unroll
            for (int i = 0; i < 4; ++i)
#pragma unroll
                for (int j = 0; j < 4; ++j)
                    acc[i][j] = fmaf(ha[i], wa[j], acc[i][j]);
        }
        __syncthreads();
    }
#pragma unroll
    for (int i = 0; i < 4; ++i) {
#pragma unroll
        for (int j = 0; j < 4; ++j) {
            int oo = o0 + tx * 4 + j;
            ys[(size_t)(t0 + ty * 4 + i) * OUTW + oo] = acc[i][j] + by[oo];
        }
    }
}

extern "C" void kernel_launch(void* const* d_in, const int* in_sizes, int n_in,
                              void* d_out, int out_size, void* d_ws, size_t ws_size,
                              hipStream_t stream) {
    const float* x   = (const float*)d_in[0];
    const float* wf  = (const float*)d_in[1];
    const float* bf  = (const float*)d_in[2];
    const float* wi  = (const float*)d_in[3];
    const float* bi  = (const float*)d_in[4];
    const float* wc  = (const float*)d_in[5];
    const float* bc  = (const float*)d_in[6];
    const float* wo  = (const float*)d_in[7];
    const float* bo  = (const float*)d_in[8];
    const float* why = (const float*)d_in[9];
    const float* by  = (const float*)d_in[10];
    float* out = (float*)d_out;

    uint64_t* hpair = (uint64_t*)d_ws;
    float* h_all = (float*)((char*)d_ws + (size_t)2 * HW * sizeof(uint64_t));

    lstm_init_kernel<<<dim3(4), dim3(256), 0, stream>>>(hpair);
    lstm_seq_kernel<<<dim3(256), dim3(256), 0, stream>>>(
        x, wf, bf, wi, bi, wc, bc, wo, bo, hpair, h_all, out);
    lstm_ygemm_kernel<<<dim3(64, 8), dim3(256), 0, stream>>>(h_all, why, by, out);
}